// Round 7
// baseline (250.409 us; speedup 1.0000x reference)
//
#include <hip/hip_runtime.h>
#include <math.h>

#define BATCH 32
#define CDIM  256
#define NDIM  1024
#define BN    (BATCH * NDIM)               // 32768
#define BNC   ((size_t)BATCH * NDIM * CDIM)
#define LN_EPSF 1e-5f
#define SCALE 0.0625f

typedef __attribute__((ext_vector_type(8))) __bf16 bf16x8;
typedef __attribute__((ext_vector_type(4))) float f32x4;
typedef __attribute__((ext_vector_type(4))) unsigned short ushort4v;

static __device__ __forceinline__ unsigned short f2bf(float f) {
  unsigned u = __float_as_uint(f);
  unsigned r = (u + 0x7FFFu + ((u >> 16) & 1u)) >> 16;   // RNE
  return (unsigned short)r;
}
static __device__ __forceinline__ float bf2f(unsigned short h) {
  return __uint_as_float(((unsigned)h) << 16);
}
static __device__ __forceinline__ void gload16(const void* g, void* l) {
  __builtin_amdgcn_global_load_lds((const __attribute__((address_space(1))) void*)g,
                                   (__attribute__((address_space(3))) void*)l, 16, 0, 0);
}

// ---------------------------------------------------------------------------
// ws layout:
//   ushort wp[4*65536]     : Whq, Wlq, Whk, Wlk   each [co][c]   (512 KB)
//   ushort planes[4*BNC]   : qh, ql, kh, kl       each [B][N][C] (67 MB)
// ---------------------------------------------------------------------------

__global__ __launch_bounds__(256) void wsplit_k(const float* __restrict__ Wq,
                                                const float* __restrict__ Wk,
                                                unsigned short* __restrict__ wp) {
  int idx = blockIdx.x * 256 + threadIdx.x;   // 0 .. 65535
  float vq = Wq[idx];
  unsigned short hq = f2bf(vq);
  wp[idx] = hq;
  wp[65536 + idx] = f2bf(vq - bf2f(hq));
  float vk = Wk[idx];
  unsigned short hk = f2bf(vk);
  wp[131072 + idx] = hk;
  wp[196608 + idx] = f2bf(vk - bf2f(hk));
}

// Fused: load x-slice -> stats -> LN -> split-bf16 -> 3-term MFMA proj ->
// split hi/lo epilogue to planes[B][N][C].
// grid: (NDIM/64, BATCH*2). 256 threads (4 waves). Block tile: 256co x 64n.
__global__ __launch_bounds__(256) void proj_k(const float* __restrict__ x,
                                              const float* __restrict__ y,
                                              const float* __restrict__ gamma,
                                              const float* __restrict__ beta,
                                              const float* __restrict__ bq,
                                              const float* __restrict__ bk,
                                              const unsigned short* __restrict__ wp,
                                              unsigned short* __restrict__ planes) {
  __shared__ unsigned short Lh[64][264];   // padded stride: 528B = 132 words = 4 mod 32
  __shared__ unsigned short Ll[64][264];
  __shared__ float psum[16][64], psq[16][64];
  __shared__ float mu[64], ri[64], gl[CDIM], bl[CDIM], bias_s[CDIM];

  const int t = threadIdx.x;
  const int bz = blockIdx.y;
  const int b = bz >> 1, which = bz & 1;
  const int n0 = blockIdx.x * 64;
  const float* src = which ? y : x;

  gl[t] = gamma[t];
  bl[t] = beta[t];
  bias_s[t] = (which ? bk : bq)[t];

  // ---- phase 1: x slice -> registers (thread: 4 n via float4, 16 c) ----
  const int nq = (t & 15) * 4;      // n offset (4 consecutive)
  const int cs = (t >> 4) * 16;     // 16 c's
  float4 xr[16];
#pragma unroll
  for (int i = 0; i < 16; ++i)
    xr[i] = *(const float4*)(src + ((size_t)b * CDIM + cs + i) * NDIM + n0 + nq);

  // ---- phase 2: stats ----
  {
    float s[4] = {0.f, 0.f, 0.f, 0.f}, q[4] = {0.f, 0.f, 0.f, 0.f};
#pragma unroll
    for (int i = 0; i < 16; ++i) {
      float v0 = xr[i].x, v1 = xr[i].y, v2 = xr[i].z, v3 = xr[i].w;
      s[0] += v0; q[0] += v0 * v0;
      s[1] += v1; q[1] += v1 * v1;
      s[2] += v2; q[2] += v2 * v2;
      s[3] += v3; q[3] += v3 * v3;
    }
#pragma unroll
    for (int j = 0; j < 4; ++j) {
      psum[t >> 4][nq + j] = s[j];
      psq[t >> 4][nq + j] = q[j];
    }
  }
  __syncthreads();
  if (t < 64) {
    float S = 0.f, Q = 0.f;
#pragma unroll
    for (int s16 = 0; s16 < 16; ++s16) { S += psum[s16][t]; Q += psq[s16][t]; }
    float m = S * (1.f / CDIM);
    mu[t] = m;
    ri[t] = rsqrtf(fmaxf(Q * (1.f / CDIM) - m * m, 0.f) + LN_EPSF);
  }
  __syncthreads();

  // ---- phase 3: LN + split -> LDS [n][c] hi/lo ----
  {
    float mj[4], rj[4];
#pragma unroll
    for (int j = 0; j < 4; ++j) { mj[j] = mu[nq + j]; rj[j] = ri[nq + j]; }
#pragma unroll
    for (int k = 0; k < 8; ++k) {
      const int c0 = cs + 2 * k, c1 = c0 + 1;
      const float g0 = gl[c0], b0 = bl[c0], g1 = gl[c1], b1 = bl[c1];
      const float u0[4] = {xr[2 * k].x, xr[2 * k].y, xr[2 * k].z, xr[2 * k].w};
      const float u1[4] = {xr[2 * k + 1].x, xr[2 * k + 1].y, xr[2 * k + 1].z, xr[2 * k + 1].w};
#pragma unroll
      for (int j = 0; j < 4; ++j) {
        float v0 = (u0[j] - mj[j]) * rj[j] * g0 + b0;
        float v1 = (u1[j] - mj[j]) * rj[j] * g1 + b1;
        unsigned short h0 = f2bf(v0), h1 = f2bf(v1);
        unsigned short e0 = f2bf(v0 - bf2f(h0)), e1 = f2bf(v1 - bf2f(h1));
        *(unsigned*)&Lh[nq + j][c0] = ((unsigned)h1 << 16) | h0;
        *(unsigned*)&Ll[nq + j][c0] = ((unsigned)e1 << 16) | e0;
      }
    }
  }
  __syncthreads();

  // ---- phase 4: MFMA. wave w: co in [w*64, w*64+64), all 64 n ----
  const int w = t >> 6, l = t & 63;
  const int l15 = l & 15, l4 = l >> 4;
  const int co_base = w * 64;
  const unsigned short* Wh = wp + (size_t)which * 131072;
  const unsigned short* Wl = Wh + 65536;

  f32x4 acc[4][4];
#pragma unroll
  for (int i = 0; i < 4; ++i)
#pragma unroll
    for (int j = 0; j < 4; ++j) acc[i][j] = (f32x4){0.f, 0.f, 0.f, 0.f};

#pragma unroll
  for (int kt = 0; kt < 8; ++kt) {
    const int c0 = kt * 32;
    bf16x8 Ah[4], Al[4], Bh[4], Bl[4];
#pragma unroll
    for (int i = 0; i < 4; ++i) {
      size_t off = (size_t)(co_base + i * 16 + l15) * CDIM + c0 + l4 * 8;
      Ah[i] = *(const bf16x8*)(Wh + off);
      Al[i] = *(const bf16x8*)(Wl + off);
    }
#pragma unroll
    for (int j = 0; j < 4; ++j) {
      Bh[j] = *(const bf16x8*)&Lh[j * 16 + l15][c0 + l4 * 8];
      Bl[j] = *(const bf16x8*)&Ll[j * 16 + l15][c0 + l4 * 8];
    }
#pragma unroll
    for (int i = 0; i < 4; ++i)
#pragma unroll
      for (int j = 0; j < 4; ++j) {
        acc[i][j] = __builtin_amdgcn_mfma_f32_16x16x32_bf16(Ah[i], Bh[j], acc[i][j], 0, 0, 0);
        acc[i][j] = __builtin_amdgcn_mfma_f32_16x16x32_bf16(Ah[i], Bl[j], acc[i][j], 0, 0, 0);
        acc[i][j] = __builtin_amdgcn_mfma_f32_16x16x32_bf16(Al[i], Bh[j], acc[i][j], 0, 0, 0);
      }
  }

  // ---- epilogue: + bias, split hi/lo, write planes [b][n][co] ----
  unsigned short* ph = planes + (size_t)which * (2 * BNC);
  unsigned short* pl = ph + BNC;
#pragma unroll
  for (int i = 0; i < 4; ++i) {
    const int co4 = co_base + i * 16 + l4 * 4;
    float bias4[4];
#pragma unroll
    for (int r = 0; r < 4; ++r) bias4[r] = bias_s[co4 + r];
#pragma unroll
    for (int j = 0; j < 4; ++j) {
      size_t base = ((size_t)b * NDIM + n0 + j * 16 + l15) * CDIM + co4;
      ushort4v hs, ls;
#pragma unroll
      for (int r = 0; r < 4; ++r) {
        float v = acc[i][j][r] + bias4[r];
        unsigned short h = f2bf(v);
        hs[r] = h;
        ls[r] = f2bf(v - bf2f(h));
      }
      *(ushort4v*)(ph + base) = hs;
      *(ushort4v*)(pl + base) = ls;
    }
  }
}

// attn: scores = Q K^T via 3-term split-bf16 MFMA, online softmax, diag out.
// R7: 2 waves/block, 32 rows/wave (2 row-frags) -> each B-frag LDS read
// feeds 2x the MFMA; per-CU LDS read traffic halves vs R3/R6 (the measured
// bottleneck). 64 phases of (m-tile 64 x c-chunk 64): 16 ds_read_b128 +
// 48 MFMA per wave per phase. Frag-linear chunks (lane l at byte l*16),
// conflict-free. 512 blocks (batch-grouped XCD swizzle), 128 threads.
__global__ __launch_bounds__(128, 2) void attn_k(const unsigned short* __restrict__ planes,
                                                 float* __restrict__ outp) {
  const unsigned short* qh = planes;
  const unsigned short* ql = planes + BNC;
  __shared__ unsigned short kbuf[2][8192];   // [dbuf][16KB]

  const int p = blockIdx.x;                      // 0..511
  const int b = (p & 7) * 4 + ((p >> 3) & 3);    // same-batch blocks -> same XCD
  const int n0 = (p >> 5) * 64;
  const int t = threadIdx.x;
  const int w = t >> 6;                          // 0..1
  const int l = t & 63;
  const int l15 = l & 15, l4 = l >> 4;

  // Q A-frags: 32 rows/wave = 2 row-frags x 8 k-frags, hi+lo (128 VGPR).
  bf16x8 ah[2][8], al[2][8];
#pragma unroll
  for (int rf = 0; rf < 2; ++rf) {
    size_t rowbase = ((size_t)b * NDIM + n0 + w * 32 + rf * 16 + l15) * CDIM + l4 * 8;
#pragma unroll
    for (int kq = 0; kq < 8; ++kq) {
      ah[rf][kq] = *(const bf16x8*)(qh + rowbase + kq * 32);
      al[rf][kq] = *(const bf16x8*)(ql + rowbase + kq * 32);
    }
  }

  const unsigned short* kb = planes + 2 * BNC + (size_t)b * NDIM * CDIM;  // kh base
  const unsigned short* lb = planes + 3 * BNC + (size_t)b * NDIM * CDIM;  // kl base

  // stage phase tt (= mt*4 + kc): 64 m-rows x 64 c, hi+lo = 16 KB.
  // chunk = (pl*2 + kf)*4 + cf ; wave w stages chunks [w*8, w*8+8).
  auto stage = [&](int buf, int tt) {
    const int mt = tt >> 2, kc = tt & 3;
#pragma unroll
    for (int ii = 0; ii < 8; ++ii) {
      const int chunk = w * 8 + ii;
      const int cf = chunk & 3, kf = (chunk >> 2) & 1, pl = chunk >> 3;
      size_t g = (size_t)(mt * 64 + cf * 16 + l15) * CDIM + kc * 64 + kf * 32 + l4 * 8;
      gload16((pl ? lb : kb) + g, &kbuf[buf][chunk * 512]);
    }
  };

  float M[8], S[8], dval[8];   // idx = rf*4 + r
#pragma unroll
  for (int i = 0; i < 8; ++i) { M[i] = -1e30f; S[i] = 0.f; dval[i] = 0.f; }

  stage(0, 0);
  __syncthreads();
  int cur = 0;

  for (int mt = 0; mt < 16; ++mt) {
    f32x4 acc[2][4];
#pragma unroll
    for (int rf = 0; rf < 2; ++rf)
#pragma unroll
      for (int cf = 0; cf < 4; ++cf) acc[rf][cf] = (f32x4){0.f, 0.f, 0.f, 0.f};

    for (int kc = 0; kc < 4; ++kc) {
      const int tt = mt * 4 + kc;
      if (tt + 1 < 64) stage(cur ^ 1, tt + 1);
#pragma unroll
      for (int kf = 0; kf < 2; ++kf) {
        const int kq = kc * 2 + kf;
#pragma unroll
        for (int cf = 0; cf < 4; ++cf) {
          bf16x8 Bh = *(const bf16x8*)&kbuf[cur][(kf * 4 + cf) * 512 + l * 8];
          bf16x8 Bl = *(const bf16x8*)&kbuf[cur][((2 + kf) * 4 + cf) * 512 + l * 8];
#pragma unroll
          for (int rf = 0; rf < 2; ++rf) {
            acc[rf][cf] = __builtin_amdgcn_mfma_f32_16x16x32_bf16(ah[rf][kq], Bh, acc[rf][cf], 0, 0, 0);
            acc[rf][cf] = __builtin_amdgcn_mfma_f32_16x16x32_bf16(ah[rf][kq], Bl, acc[rf][cf], 0, 0, 0);
            acc[rf][cf] = __builtin_amdgcn_mfma_f32_16x16x32_bf16(al[rf][kq], Bh, acc[rf][cf], 0, 0, 0);
          }
        }
      }
      __syncthreads();
      cur ^= 1;
    }

    // online softmax over this 64-col tile. C/D: col=l15, row=l4*4+r.
#pragma unroll
    for (int rf = 0; rf < 2; ++rf) {
#pragma unroll
      for (int r = 0; r < 4; ++r) {
        const int idx = rf * 4 + r;
        const int n = n0 + w * 32 + rf * 16 + l4 * 4 + r;
        float tm = -1e30f;
#pragma unroll
        for (int cf = 0; cf < 4; ++cf) tm = fmaxf(tm, acc[rf][cf][r]);
        tm *= SCALE;
#pragma unroll
        for (int off = 8; off >= 1; off >>= 1) tm = fmaxf(tm, __shfl_xor(tm, off));
        const float Mn = fmaxf(M[idx], tm);
        float ps = 0.f;
#pragma unroll
        for (int cf = 0; cf < 4; ++cf) ps += __expf(acc[rf][cf][r] * SCALE - Mn);
#pragma unroll
        for (int off = 8; off >= 1; off >>= 1) ps += __shfl_xor(ps, off);
        S[idx] = S[idx] * __expf(M[idx] - Mn) + ps;
        M[idx] = Mn;
#pragma unroll
        for (int cf = 0; cf < 4; ++cf)
          if (mt * 64 + cf * 16 + l15 == n) dval[idx] = acc[rf][cf][r] * SCALE;
      }
    }
  }

#pragma unroll
  for (int rf = 0; rf < 2; ++rf)
#pragma unroll
    for (int r = 0; r < 4; ++r) {
      const int idx = rf * 4 + r;
      const int n = n0 + w * 32 + rf * 16 + l4 * 4 + r;
      if (l15 == l4 * 4 + r)
        outp[(size_t)b * NDIM + n] = __expf(dval[idx] - M[idx]) / S[idx];
    }
}

extern "C" void kernel_launch(void* const* d_in, const int* in_sizes, int n_in,
                              void* d_out, int out_size, void* d_ws, size_t ws_size,
                              hipStream_t stream) {
  (void)in_sizes; (void)n_in; (void)out_size; (void)ws_size;
  const float* x     = (const float*)d_in[0];
  const float* y     = (const float*)d_in[1];
  const float* gamma = (const float*)d_in[2];
  const float* beta  = (const float*)d_in[3];
  const float* Wq    = (const float*)d_in[4];
  const float* Wk    = (const float*)d_in[5];
  const float* bq    = (const float*)d_in[6];
  const float* bk    = (const float*)d_in[7];
  float* out = (float*)d_out;

  unsigned short* wp = (unsigned short*)d_ws;
  unsigned short* planes = wp + 262144;

  wsplit_k<<<256, 256, 0, stream>>>(Wq, Wk, wp);

  dim3 g2(NDIM / 64, BATCH * 2);
  proj_k<<<g2, 256, 0, stream>>>(x, y, gamma, beta, bq, bk, wp, planes);

  attn_k<<<512, 128, 0, stream>>>(planes, out);
}

// Round 8
// 215.302 us; speedup vs baseline: 1.1631x; 1.1631x over previous
//
#include <hip/hip_runtime.h>
#include <math.h>

#define BATCH 32
#define CDIM  256
#define NDIM  1024
#define BN    (BATCH * NDIM)               // 32768
#define BNC   ((size_t)BATCH * NDIM * CDIM)
#define LN_EPSF 1e-5f
#define SCALE 0.0625f

typedef __attribute__((ext_vector_type(8))) __bf16 bf16x8;
typedef __attribute__((ext_vector_type(4))) float f32x4;
typedef __attribute__((ext_vector_type(4))) unsigned short ushort4v;

static __device__ __forceinline__ unsigned short f2bf(float f) {
  unsigned u = __float_as_uint(f);
  unsigned r = (u + 0x7FFFu + ((u >> 16) & 1u)) >> 16;   // RNE
  return (unsigned short)r;
}
static __device__ __forceinline__ float bf2f(unsigned short h) {
  return __uint_as_float(((unsigned)h) << 16);
}
static __device__ __forceinline__ void gload16(const void* g, void* l) {
  __builtin_amdgcn_global_load_lds((const __attribute__((address_space(1))) void*)g,
                                   (__attribute__((address_space(3))) void*)l, 16, 0, 0);
}

// ---------------------------------------------------------------------------
// ws layout:
//   ushort wp[4*65536]     : Whq, Wlq, Whk, Wlk   each [co][c]   (512 KB)
//   ushort planes[4*BNC]   : qh, ql, kh, kl       each [B][N][C] (67 MB)
//   float  part[5*BN]      : Mp[2][BN], Sp[2][BN], dv[BN]        (640 KB)
// ---------------------------------------------------------------------------

__global__ __launch_bounds__(256) void wsplit_k(const float* __restrict__ Wq,
                                                const float* __restrict__ Wk,
                                                unsigned short* __restrict__ wp) {
  int idx = blockIdx.x * 256 + threadIdx.x;   // 0 .. 65535
  float vq = Wq[idx];
  unsigned short hq = f2bf(vq);
  wp[idx] = hq;
  wp[65536 + idx] = f2bf(vq - bf2f(hq));
  float vk = Wk[idx];
  unsigned short hk = f2bf(vk);
  wp[131072 + idx] = hk;
  wp[196608 + idx] = f2bf(vk - bf2f(hk));
}

// Fused: load x-slice -> stats -> LN -> split-bf16 -> 3-term MFMA proj ->
// split hi/lo epilogue to planes[B][N][C].
// grid: (NDIM/64, BATCH*2). 256 threads (4 waves). Block tile: 256co x 64n.
__global__ __launch_bounds__(256) void proj_k(const float* __restrict__ x,
                                              const float* __restrict__ y,
                                              const float* __restrict__ gamma,
                                              const float* __restrict__ beta,
                                              const float* __restrict__ bq,
                                              const float* __restrict__ bk,
                                              const unsigned short* __restrict__ wp,
                                              unsigned short* __restrict__ planes) {
  __shared__ unsigned short Lh[64][264];   // padded stride: 528B = 132 words = 4 mod 32
  __shared__ unsigned short Ll[64][264];
  __shared__ float psum[16][64], psq[16][64];
  __shared__ float mu[64], ri[64], gl[CDIM], bl[CDIM], bias_s[CDIM];

  const int t = threadIdx.x;
  const int bz = blockIdx.y;
  const int b = bz >> 1, which = bz & 1;
  const int n0 = blockIdx.x * 64;
  const float* src = which ? y : x;

  gl[t] = gamma[t];
  bl[t] = beta[t];
  bias_s[t] = (which ? bk : bq)[t];

  // ---- phase 1: x slice -> registers (thread: 4 n via float4, 16 c) ----
  const int nq = (t & 15) * 4;      // n offset (4 consecutive)
  const int cs = (t >> 4) * 16;     // 16 c's
  float4 xr[16];
#pragma unroll
  for (int i = 0; i < 16; ++i)
    xr[i] = *(const float4*)(src + ((size_t)b * CDIM + cs + i) * NDIM + n0 + nq);

  // ---- phase 2: stats ----
  {
    float s[4] = {0.f, 0.f, 0.f, 0.f}, q[4] = {0.f, 0.f, 0.f, 0.f};
#pragma unroll
    for (int i = 0; i < 16; ++i) {
      float v0 = xr[i].x, v1 = xr[i].y, v2 = xr[i].z, v3 = xr[i].w;
      s[0] += v0; q[0] += v0 * v0;
      s[1] += v1; q[1] += v1 * v1;
      s[2] += v2; q[2] += v2 * v2;
      s[3] += v3; q[3] += v3 * v3;
    }
#pragma unroll
    for (int j = 0; j < 4; ++j) {
      psum[t >> 4][nq + j] = s[j];
      psq[t >> 4][nq + j] = q[j];
    }
  }
  __syncthreads();
  if (t < 64) {
    float S = 0.f, Q = 0.f;
#pragma unroll
    for (int s16 = 0; s16 < 16; ++s16) { S += psum[s16][t]; Q += psq[s16][t]; }
    float m = S * (1.f / CDIM);
    mu[t] = m;
    ri[t] = rsqrtf(fmaxf(Q * (1.f / CDIM) - m * m, 0.f) + LN_EPSF);
  }
  __syncthreads();

  // ---- phase 3: LN + split -> LDS [n][c] hi/lo ----
  {
    float mj[4], rj[4];
#pragma unroll
    for (int j = 0; j < 4; ++j) { mj[j] = mu[nq + j]; rj[j] = ri[nq + j]; }
#pragma unroll
    for (int k = 0; k < 8; ++k) {
      const int c0 = cs + 2 * k, c1 = c0 + 1;
      const float g0 = gl[c0], b0 = bl[c0], g1 = gl[c1], b1 = bl[c1];
      const float u0[4] = {xr[2 * k].x, xr[2 * k].y, xr[2 * k].z, xr[2 * k].w};
      const float u1[4] = {xr[2 * k + 1].x, xr[2 * k + 1].y, xr[2 * k + 1].z, xr[2 * k + 1].w};
#pragma unroll
      for (int j = 0; j < 4; ++j) {
        float v0 = (u0[j] - mj[j]) * rj[j] * g0 + b0;
        float v1 = (u1[j] - mj[j]) * rj[j] * g1 + b1;
        unsigned short h0 = f2bf(v0), h1 = f2bf(v1);
        unsigned short e0 = f2bf(v0 - bf2f(h0)), e1 = f2bf(v1 - bf2f(h1));
        *(unsigned*)&Lh[nq + j][c0] = ((unsigned)h1 << 16) | h0;
        *(unsigned*)&Ll[nq + j][c0] = ((unsigned)e1 << 16) | e0;
      }
    }
  }
  __syncthreads();

  // ---- phase 4: MFMA. wave w: co in [w*64, w*64+64), all 64 n ----
  const int w = t >> 6, l = t & 63;
  const int l15 = l & 15, l4 = l >> 4;
  const int co_base = w * 64;
  const unsigned short* Wh = wp + (size_t)which * 131072;
  const unsigned short* Wl = Wh + 65536;

  f32x4 acc[4][4];
#pragma unroll
  for (int i = 0; i < 4; ++i)
#pragma unroll
    for (int j = 0; j < 4; ++j) acc[i][j] = (f32x4){0.f, 0.f, 0.f, 0.f};

#pragma unroll
  for (int kt = 0; kt < 8; ++kt) {
    const int c0 = kt * 32;
    bf16x8 Ah[4], Al[4], Bh[4], Bl[4];
#pragma unroll
    for (int i = 0; i < 4; ++i) {
      size_t off = (size_t)(co_base + i * 16 + l15) * CDIM + c0 + l4 * 8;
      Ah[i] = *(const bf16x8*)(Wh + off);
      Al[i] = *(const bf16x8*)(Wl + off);
    }
#pragma unroll
    for (int j = 0; j < 4; ++j) {
      Bh[j] = *(const bf16x8*)&Lh[j * 16 + l15][c0 + l4 * 8];
      Bl[j] = *(const bf16x8*)&Ll[j * 16 + l15][c0 + l4 * 8];
    }
#pragma unroll
    for (int i = 0; i < 4; ++i)
#pragma unroll
      for (int j = 0; j < 4; ++j) {
        acc[i][j] = __builtin_amdgcn_mfma_f32_16x16x32_bf16(Ah[i], Bh[j], acc[i][j], 0, 0, 0);
        acc[i][j] = __builtin_amdgcn_mfma_f32_16x16x32_bf16(Ah[i], Bl[j], acc[i][j], 0, 0, 0);
        acc[i][j] = __builtin_amdgcn_mfma_f32_16x16x32_bf16(Al[i], Bh[j], acc[i][j], 0, 0, 0);
      }
  }

  // ---- epilogue: + bias, split hi/lo, write planes [b][n][co] ----
  unsigned short* ph = planes + (size_t)which * (2 * BNC);
  unsigned short* pl = ph + BNC;
#pragma unroll
  for (int i = 0; i < 4; ++i) {
    const int co4 = co_base + i * 16 + l4 * 4;
    float bias4[4];
#pragma unroll
    for (int r = 0; r < 4; ++r) bias4[r] = bias_s[co4 + r];
#pragma unroll
    for (int j = 0; j < 4; ++j) {
      size_t base = ((size_t)b * NDIM + n0 + j * 16 + l15) * CDIM + co4;
      ushort4v hs, ls;
#pragma unroll
      for (int r = 0; r < 4; ++r) {
        float v = acc[i][j][r] + bias4[r];
        unsigned short h = f2bf(v);
        hs[r] = h;
        ls[r] = f2bf(v - bf2f(h));
      }
      *(ushort4v*)(ph + base) = hs;
      *(ushort4v*)(pl + base) = ls;
    }
  }
}

// attn: scores = Q K^T via 3-term split-bf16 MFMA, online softmax partials.
// R8: 4 waves x 32 rows/wave (128 Q-rows/block) x K-split 2 (512 K-rows).
// Per-wave LDS read halves vs R3 (B-frag feeds 2 A-pairs) while total waves
// stay 2048 (= 8/CU = 2/SIMD). Partial (M,S,dval) per K-half -> merge_k.
// Phases: 64 K-rows x 64 c (16 KB, dbuf). 512 blocks, 256 threads.
__global__ __launch_bounds__(256, 2) void attn_k(const unsigned short* __restrict__ planes,
                                                 float* __restrict__ part) {
  const unsigned short* qh = planes;
  const unsigned short* ql = planes + BNC;
  __shared__ unsigned short kbuf[2][8192];   // [dbuf][16KB]

  const int p = blockIdx.x;                      // 0..511
  const int b = (p & 7) * 4 + ((p >> 3) & 3);    // same-batch blocks -> same XCD
  const int rest = p >> 5;                       // 0..15
  const int qt = rest & 7;                       // Q tile (128 rows)
  const int ks = rest >> 3;                      // K half
  const int n0 = qt * 128;
  const int k0 = ks * 512;
  const int t = threadIdx.x;
  const int w = t >> 6;                          // 0..3
  const int l = t & 63;
  const int l15 = l & 15, l4 = l >> 4;

  // Q A-frags: 32 rows/wave = 2 row-frags x 8 k-frags, hi+lo.
  bf16x8 ah[2][8], al[2][8];
#pragma unroll
  for (int rf = 0; rf < 2; ++rf) {
    size_t rowbase = ((size_t)b * NDIM + n0 + w * 32 + rf * 16 + l15) * CDIM + l4 * 8;
#pragma unroll
    for (int kq = 0; kq < 8; ++kq) {
      ah[rf][kq] = *(const bf16x8*)(qh + rowbase + kq * 32);
      al[rf][kq] = *(const bf16x8*)(ql + rowbase + kq * 32);
    }
  }

  const unsigned short* kb = planes + 2 * BNC + (size_t)b * NDIM * CDIM;  // kh base
  const unsigned short* lb = planes + 3 * BNC + (size_t)b * NDIM * CDIM;  // kl base

  // stage phase tt (= mt*4 + kc): 64 K-rows x 64 c, hi+lo = 16 KB.
  // chunk = pl*8 + kf*4 + f ; wave w stages chunks [w*4, w*4+4).
  auto stage = [&](int buf, int tt) {
    const int mt = tt >> 2, kc = tt & 3;
#pragma unroll
    for (int ii = 0; ii < 4; ++ii) {
      const int chunk = w * 4 + ii;
      const int f = chunk & 3, kf = (chunk >> 2) & 1, pl = chunk >> 3;
      size_t g = (size_t)(k0 + mt * 64 + f * 16 + l15) * CDIM + kc * 64 + kf * 32 + l4 * 8;
      gload16((pl ? lb : kb) + g, &kbuf[buf][chunk * 512]);
    }
  };

  float M[8], S[8], dval[8];   // idx = rf*4 + r
#pragma unroll
  for (int i = 0; i < 8; ++i) { M[i] = -1e30f; S[i] = 0.f; dval[i] = 0.f; }

  stage(0, 0);
  __syncthreads();
  int cur = 0;

  for (int mt = 0; mt < 8; ++mt) {
    f32x4 acc[2][4];
#pragma unroll
    for (int rf = 0; rf < 2; ++rf)
#pragma unroll
      for (int cf = 0; cf < 4; ++cf) acc[rf][cf] = (f32x4){0.f, 0.f, 0.f, 0.f};

    for (int kc = 0; kc < 4; ++kc) {
      const int tt = mt * 4 + kc;
      if (tt + 1 < 32) stage(cur ^ 1, tt + 1);
#pragma unroll
      for (int kf = 0; kf < 2; ++kf) {
        const int kq = kc * 2 + kf;
#pragma unroll
        for (int cf = 0; cf < 4; ++cf) {
          bf16x8 Bh = *(const bf16x8*)&kbuf[cur][(kf * 4 + cf) * 512 + l * 8];
          bf16x8 Bl = *(const bf16x8*)&kbuf[cur][(8 + kf * 4 + cf) * 512 + l * 8];
#pragma unroll
          for (int rf = 0; rf < 2; ++rf) {
            acc[rf][cf] = __builtin_amdgcn_mfma_f32_16x16x32_bf16(ah[rf][kq], Bh, acc[rf][cf], 0, 0, 0);
            acc[rf][cf] = __builtin_amdgcn_mfma_f32_16x16x32_bf16(ah[rf][kq], Bl, acc[rf][cf], 0, 0, 0);
            acc[rf][cf] = __builtin_amdgcn_mfma_f32_16x16x32_bf16(al[rf][kq], Bh, acc[rf][cf], 0, 0, 0);
          }
        }
      }
      __syncthreads();
      cur ^= 1;
    }

    // online softmax over this 64-col tile (K cols k0 + mt*64 + cf*16 + l15).
#pragma unroll
    for (int rf = 0; rf < 2; ++rf) {
#pragma unroll
      for (int r = 0; r < 4; ++r) {
        const int idx = rf * 4 + r;
        const int n = n0 + w * 32 + rf * 16 + l4 * 4 + r;
        float tm = -1e30f;
#pragma unroll
        for (int cf = 0; cf < 4; ++cf) tm = fmaxf(tm, acc[rf][cf][r]);
        tm *= SCALE;
#pragma unroll
        for (int off = 8; off >= 1; off >>= 1) tm = fmaxf(tm, __shfl_xor(tm, off));
        const float Mn = fmaxf(M[idx], tm);
        float ps = 0.f;
#pragma unroll
        for (int cf = 0; cf < 4; ++cf) ps += __expf(acc[rf][cf][r] * SCALE - Mn);
#pragma unroll
        for (int off = 8; off >= 1; off >>= 1) ps += __shfl_xor(ps, off);
        S[idx] = S[idx] * __expf(M[idx] - Mn) + ps;
        M[idx] = Mn;
#pragma unroll
        for (int cf = 0; cf < 4; ++cf)
          if (k0 + mt * 64 + cf * 16 + l15 == n) dval[idx] = acc[rf][cf][r] * SCALE;
      }
    }
  }

  // write partials: Mp[ks][b][n], Sp[ks][b][n]; dv[b][n] from the diag owner.
  float* Mp = part;
  float* Sp = part + 2 * BN;
  float* dv = part + 4 * BN;
#pragma unroll
  for (int rf = 0; rf < 2; ++rf)
#pragma unroll
    for (int r = 0; r < 4; ++r) {
      const int idx = rf * 4 + r;
      const int n = n0 + w * 32 + rf * 16 + l4 * 4 + r;
      if (l15 == l4 * 4 + r) {
        Mp[ks * BN + b * NDIM + n] = M[idx];
        Sp[ks * BN + b * NDIM + n] = S[idx];
        if ((n >> 9) == ks) dv[b * NDIM + n] = dval[idx];
      }
    }
}

// merge the two K-half partials into final diag probability.
__global__ __launch_bounds__(256) void merge_k(const float* __restrict__ part,
                                               float* __restrict__ outp) {
  const int gid = blockIdx.x * 256 + threadIdx.x;   // 0..BN
  const float M0 = part[gid], M1 = part[BN + gid];
  const float S0 = part[2 * BN + gid], S1 = part[3 * BN + gid];
  const float d = part[4 * BN + gid];
  const float Mf = fmaxf(M0, M1);
  const float Sf = S0 * __expf(M0 - Mf) + S1 * __expf(M1 - Mf);
  outp[gid] = __expf(d - Mf) / Sf;
}

extern "C" void kernel_launch(void* const* d_in, const int* in_sizes, int n_in,
                              void* d_out, int out_size, void* d_ws, size_t ws_size,
                              hipStream_t stream) {
  (void)in_sizes; (void)n_in; (void)out_size; (void)ws_size;
  const float* x     = (const float*)d_in[0];
  const float* y     = (const float*)d_in[1];
  const float* gamma = (const float*)d_in[2];
  const float* beta  = (const float*)d_in[3];
  const float* Wq    = (const float*)d_in[4];
  const float* Wk    = (const float*)d_in[5];
  const float* bq    = (const float*)d_in[6];
  const float* bk    = (const float*)d_in[7];
  float* out = (float*)d_out;

  unsigned short* wp = (unsigned short*)d_ws;
  unsigned short* planes = wp + 262144;
  float* part = (float*)(planes + 4 * BNC);

  wsplit_k<<<256, 256, 0, stream>>>(Wq, Wk, wp);

  dim3 g2(NDIM / 64, BATCH * 2);
  proj_k<<<g2, 256, 0, stream>>>(x, y, gamma, beta, bq, bk, wp, planes);

  attn_k<<<512, 256, 0, stream>>>(planes, part);

  merge_k<<<BN / 256, 256, 0, stream>>>(part, out);
}

// Round 9
// 210.994 us; speedup vs baseline: 1.1868x; 1.0204x over previous
//
#include <hip/hip_runtime.h>
#include <math.h>

#define BATCH 32
#define CDIM  256
#define NDIM  1024
#define BN    (BATCH * NDIM)               // 32768
#define BNC   ((size_t)BATCH * NDIM * CDIM)
#define LN_EPSF 1e-5f
#define SCALE 0.0625f

typedef __attribute__((ext_vector_type(8))) __bf16 bf16x8;
typedef __attribute__((ext_vector_type(4))) float f32x4;
typedef __attribute__((ext_vector_type(4))) unsigned short ushort4v;

static __device__ __forceinline__ unsigned short f2bf(float f) {
  unsigned u = __float_as_uint(f);
  unsigned r = (u + 0x7FFFu + ((u >> 16) & 1u)) >> 16;   // RNE
  return (unsigned short)r;
}
static __device__ __forceinline__ float bf2f(unsigned short h) {
  return __uint_as_float(((unsigned)h) << 16);
}
static __device__ __forceinline__ void gload16(const void* g, void* l) {
  __builtin_amdgcn_global_load_lds((const __attribute__((address_space(1))) void*)g,
                                   (__attribute__((address_space(3))) void*)l, 16, 0, 0);
}

// ---------------------------------------------------------------------------
// ws layout:
//   ushort wp[4*65536]     : Whq, Wlq, Whk, Wlk   each [co][c]   (512 KB)
//   ushort planes[4*BNC]   : qh, ql, kh, kl       each [B][N][C] (67 MB)
//   float  part[5*BN]      : Mp[2][BN], Sp[2][BN], dv[BN]        (640 KB)
// ---------------------------------------------------------------------------

__global__ __launch_bounds__(256) void wsplit_k(const float* __restrict__ Wq,
                                                const float* __restrict__ Wk,
                                                unsigned short* __restrict__ wp) {
  int idx = blockIdx.x * 256 + threadIdx.x;   // 0 .. 65535
  float vq = Wq[idx];
  unsigned short hq = f2bf(vq);
  wp[idx] = hq;
  wp[65536 + idx] = f2bf(vq - bf2f(hq));
  float vk = Wk[idx];
  unsigned short hk = f2bf(vk);
  wp[131072 + idx] = hk;
  wp[196608 + idx] = f2bf(vk - bf2f(hk));
}

// Fused: load x-slice -> stats -> LN -> split-bf16 -> 3-term MFMA proj ->
// split hi/lo epilogue to planes[B][N][C].
// grid: (NDIM/64, BATCH*2). 256 threads (4 waves). Block tile: 256co x 64n.
__global__ __launch_bounds__(256) void proj_k(const float* __restrict__ x,
                                              const float* __restrict__ y,
                                              const float* __restrict__ gamma,
                                              const float* __restrict__ beta,
                                              const float* __restrict__ bq,
                                              const float* __restrict__ bk,
                                              const unsigned short* __restrict__ wp,
                                              unsigned short* __restrict__ planes) {
  __shared__ unsigned short Lh[64][264];   // padded stride: 528B = 132 words = 4 mod 32
  __shared__ unsigned short Ll[64][264];
  __shared__ float psum[16][64], psq[16][64];
  __shared__ float mu[64], ri[64], gl[CDIM], bl[CDIM], bias_s[CDIM];

  const int t = threadIdx.x;
  const int bz = blockIdx.y;
  const int b = bz >> 1, which = bz & 1;
  const int n0 = blockIdx.x * 64;
  const float* src = which ? y : x;

  gl[t] = gamma[t];
  bl[t] = beta[t];
  bias_s[t] = (which ? bk : bq)[t];

  // ---- phase 1: x slice -> registers (thread: 4 n via float4, 16 c) ----
  const int nq = (t & 15) * 4;      // n offset (4 consecutive)
  const int cs = (t >> 4) * 16;     // 16 c's
  float4 xr[16];
#pragma unroll
  for (int i = 0; i < 16; ++i)
    xr[i] = *(const float4*)(src + ((size_t)b * CDIM + cs + i) * NDIM + n0 + nq);

  // ---- phase 2: stats ----
  {
    float s[4] = {0.f, 0.f, 0.f, 0.f}, q[4] = {0.f, 0.f, 0.f, 0.f};
#pragma unroll
    for (int i = 0; i < 16; ++i) {
      float v0 = xr[i].x, v1 = xr[i].y, v2 = xr[i].z, v3 = xr[i].w;
      s[0] += v0; q[0] += v0 * v0;
      s[1] += v1; q[1] += v1 * v1;
      s[2] += v2; q[2] += v2 * v2;
      s[3] += v3; q[3] += v3 * v3;
    }
#pragma unroll
    for (int j = 0; j < 4; ++j) {
      psum[t >> 4][nq + j] = s[j];
      psq[t >> 4][nq + j] = q[j];
    }
  }
  __syncthreads();
  if (t < 64) {
    float S = 0.f, Q = 0.f;
#pragma unroll
    for (int s16 = 0; s16 < 16; ++s16) { S += psum[s16][t]; Q += psq[s16][t]; }
    float m = S * (1.f / CDIM);
    mu[t] = m;
    ri[t] = rsqrtf(fmaxf(Q * (1.f / CDIM) - m * m, 0.f) + LN_EPSF);
  }
  __syncthreads();

  // ---- phase 3: LN + split -> LDS [n][c] hi/lo ----
  {
    float mj[4], rj[4];
#pragma unroll
    for (int j = 0; j < 4; ++j) { mj[j] = mu[nq + j]; rj[j] = ri[nq + j]; }
#pragma unroll
    for (int k = 0; k < 8; ++k) {
      const int c0 = cs + 2 * k, c1 = c0 + 1;
      const float g0 = gl[c0], b0 = bl[c0], g1 = gl[c1], b1 = bl[c1];
      const float u0[4] = {xr[2 * k].x, xr[2 * k].y, xr[2 * k].z, xr[2 * k].w};
      const float u1[4] = {xr[2 * k + 1].x, xr[2 * k + 1].y, xr[2 * k + 1].z, xr[2 * k + 1].w};
#pragma unroll
      for (int j = 0; j < 4; ++j) {
        float v0 = (u0[j] - mj[j]) * rj[j] * g0 + b0;
        float v1 = (u1[j] - mj[j]) * rj[j] * g1 + b1;
        unsigned short h0 = f2bf(v0), h1 = f2bf(v1);
        unsigned short e0 = f2bf(v0 - bf2f(h0)), e1 = f2bf(v1 - bf2f(h1));
        *(unsigned*)&Lh[nq + j][c0] = ((unsigned)h1 << 16) | h0;
        *(unsigned*)&Ll[nq + j][c0] = ((unsigned)e1 << 16) | e0;
      }
    }
  }
  __syncthreads();

  // ---- phase 4: MFMA. wave w: co in [w*64, w*64+64), all 64 n ----
  const int w = t >> 6, l = t & 63;
  const int l15 = l & 15, l4 = l >> 4;
  const int co_base = w * 64;
  const unsigned short* Wh = wp + (size_t)which * 131072;
  const unsigned short* Wl = Wh + 65536;

  f32x4 acc[4][4];
#pragma unroll
  for (int i = 0; i < 4; ++i)
#pragma unroll
    for (int j = 0; j < 4; ++j) acc[i][j] = (f32x4){0.f, 0.f, 0.f, 0.f};

#pragma unroll
  for (int kt = 0; kt < 8; ++kt) {
    const int c0 = kt * 32;
    bf16x8 Ah[4], Al[4], Bh[4], Bl[4];
#pragma unroll
    for (int i = 0; i < 4; ++i) {
      size_t off = (size_t)(co_base + i * 16 + l15) * CDIM + c0 + l4 * 8;
      Ah[i] = *(const bf16x8*)(Wh + off);
      Al[i] = *(const bf16x8*)(Wl + off);
    }
#pragma unroll
    for (int j = 0; j < 4; ++j) {
      Bh[j] = *(const bf16x8*)&Lh[j * 16 + l15][c0 + l4 * 8];
      Bl[j] = *(const bf16x8*)&Ll[j * 16 + l15][c0 + l4 * 8];
    }
#pragma unroll
    for (int i = 0; i < 4; ++i)
#pragma unroll
      for (int j = 0; j < 4; ++j) {
        acc[i][j] = __builtin_amdgcn_mfma_f32_16x16x32_bf16(Ah[i], Bh[j], acc[i][j], 0, 0, 0);
        acc[i][j] = __builtin_amdgcn_mfma_f32_16x16x32_bf16(Ah[i], Bl[j], acc[i][j], 0, 0, 0);
        acc[i][j] = __builtin_amdgcn_mfma_f32_16x16x32_bf16(Al[i], Bh[j], acc[i][j], 0, 0, 0);
      }
  }

  // ---- epilogue: + bias, split hi/lo, write planes [b][n][co] ----
  unsigned short* ph = planes + (size_t)which * (2 * BNC);
  unsigned short* pl = ph + BNC;
#pragma unroll
  for (int i = 0; i < 4; ++i) {
    const int co4 = co_base + i * 16 + l4 * 4;
    float bias4[4];
#pragma unroll
    for (int r = 0; r < 4; ++r) bias4[r] = bias_s[co4 + r];
#pragma unroll
    for (int j = 0; j < 4; ++j) {
      size_t base = ((size_t)b * NDIM + n0 + j * 16 + l15) * CDIM + co4;
      ushort4v hs, ls;
#pragma unroll
      for (int r = 0; r < 4; ++r) {
        float v = acc[i][j][r] + bias4[r];
        unsigned short h = f2bf(v);
        hs[r] = h;
        ls[r] = f2bf(v - bf2f(h));
      }
      *(ushort4v*)(ph + base) = hs;
      *(ushort4v*)(pl + base) = ls;
    }
  }
}

// attn: scores = Q K^T via 3-term split-bf16 MFMA, online softmax partials.
// R9: T3/T4 counted-vmcnt pipeline. 4-buffer LDS rotation (4 x 16 KB),
// stage depth 2 (phase t issues tile t+2), per-phase ending is
// `s_waitcnt vmcnt(4)` + raw s_barrier — the DMA queue is never drained
// to 0 in the main loop. Safety: buf (t+2)&3 was last read at phase t-2
// (two barriers ago); vmcnt(4) before the barrier guarantees every wave's
// tile-(t+1) loads landed, so after the barrier buf[(t+1)&3] is ready.
// 4 waves x 32 rows/wave x K-split 2. 512 blocks, 256 threads.
__global__ __launch_bounds__(256, 2) void attn_k(const unsigned short* __restrict__ planes,
                                                 float* __restrict__ part) {
  const unsigned short* qh = planes;
  const unsigned short* ql = planes + BNC;
  __shared__ unsigned short kbuf[4][8192];   // 4 x 16 KB rotation

  const int p = blockIdx.x;                      // 0..511
  const int b = (p & 7) * 4 + ((p >> 3) & 3);    // same-batch blocks -> same XCD
  const int rest = p >> 5;                       // 0..15
  const int qt = rest & 7;                       // Q tile (128 rows)
  const int ks = rest >> 3;                      // K half
  const int n0 = qt * 128;
  const int k0 = ks * 512;
  const int t = threadIdx.x;
  const int w = t >> 6;                          // 0..3
  const int l = t & 63;
  const int l15 = l & 15, l4 = l >> 4;

  // Q A-frags: 32 rows/wave = 2 row-frags x 8 k-frags, hi+lo (128 VGPR).
  bf16x8 ah[2][8], al[2][8];
#pragma unroll
  for (int rf = 0; rf < 2; ++rf) {
    size_t rowbase = ((size_t)b * NDIM + n0 + w * 32 + rf * 16 + l15) * CDIM + l4 * 8;
#pragma unroll
    for (int kq = 0; kq < 8; ++kq) {
      ah[rf][kq] = *(const bf16x8*)(qh + rowbase + kq * 32);
      al[rf][kq] = *(const bf16x8*)(ql + rowbase + kq * 32);
    }
  }

  const unsigned short* kb = planes + 2 * BNC + (size_t)b * NDIM * CDIM;  // kh base
  const unsigned short* lb = planes + 3 * BNC + (size_t)b * NDIM * CDIM;  // kl base

  // stage phase tt (= mt*4 + kc): 64 K-rows x 64 c, hi+lo = 16 KB.
  // chunk = pl*8 + kf*4 + f ; wave w stages chunks [w*4, w*4+4) = 4 loads.
  auto stage = [&](int buf, int tt) {
    const int mt = tt >> 2, kc = tt & 3;
#pragma unroll
    for (int ii = 0; ii < 4; ++ii) {
      const int chunk = w * 4 + ii;
      const int f = chunk & 3, kf = (chunk >> 2) & 1, pl = chunk >> 3;
      size_t g = (size_t)(k0 + mt * 64 + f * 16 + l15) * CDIM + kc * 64 + kf * 32 + l4 * 8;
      gload16((pl ? lb : kb) + g, &kbuf[buf][chunk * 512]);
    }
  };

  float M[8], S[8], dval[8];   // idx = rf*4 + r
#pragma unroll
  for (int i = 0; i < 8; ++i) { M[i] = -1e30f; S[i] = 0.f; dval[i] = 0.f; }

  // prologue: fill depth-2 pipeline; require tile 0 landed (tile 1 in flight)
  stage(0, 0);
  stage(1, 1);
  asm volatile("s_waitcnt vmcnt(4)" ::: "memory");
  __builtin_amdgcn_s_barrier();

  for (int mt = 0; mt < 8; ++mt) {
    f32x4 acc[2][4];
#pragma unroll
    for (int rf = 0; rf < 2; ++rf)
#pragma unroll
      for (int cf = 0; cf < 4; ++cf) acc[rf][cf] = (f32x4){0.f, 0.f, 0.f, 0.f};

    for (int kc = 0; kc < 4; ++kc) {
      const int tt = mt * 4 + kc;
      if (tt + 2 < 32) stage((tt + 2) & 3, tt + 2);
      const unsigned short* bp = &kbuf[tt & 3][0];
      __builtin_amdgcn_s_setprio(1);
#pragma unroll
      for (int kf = 0; kf < 2; ++kf) {
        const int kq = kc * 2 + kf;
#pragma unroll
        for (int cf = 0; cf < 4; ++cf) {
          bf16x8 Bh = *(const bf16x8*)(bp + (kf * 4 + cf) * 512 + l * 8);
          bf16x8 Bl = *(const bf16x8*)(bp + (8 + kf * 4 + cf) * 512 + l * 8);
#pragma unroll
          for (int rf = 0; rf < 2; ++rf) {
            acc[rf][cf] = __builtin_amdgcn_mfma_f32_16x16x32_bf16(ah[rf][kq], Bh, acc[rf][cf], 0, 0, 0);
            acc[rf][cf] = __builtin_amdgcn_mfma_f32_16x16x32_bf16(ah[rf][kq], Bl, acc[rf][cf], 0, 0, 0);
            acc[rf][cf] = __builtin_amdgcn_mfma_f32_16x16x32_bf16(al[rf][kq], Bh, acc[rf][cf], 0, 0, 0);
          }
        }
      }
      __builtin_amdgcn_s_setprio(0);
      // counted wait: allow tile t+2's 4 loads in flight; force t+1's landed.
      if (tt + 2 < 32) {
        asm volatile("s_waitcnt vmcnt(4)" ::: "memory");
        __builtin_amdgcn_s_barrier();
      } else if (tt == 30) {
        asm volatile("s_waitcnt vmcnt(0)" ::: "memory");
        __builtin_amdgcn_s_barrier();
      }
      // tt == 31: last tile, no further LDS reads -> no barrier needed.
    }

    // online softmax over this 64-col tile (K cols k0 + mt*64 + cf*16 + l15).
#pragma unroll
    for (int rf = 0; rf < 2; ++rf) {
#pragma unroll
      for (int r = 0; r < 4; ++r) {
        const int idx = rf * 4 + r;
        const int n = n0 + w * 32 + rf * 16 + l4 * 4 + r;
        float tm = -1e30f;
#pragma unroll
        for (int cf = 0; cf < 4; ++cf) tm = fmaxf(tm, acc[rf][cf][r]);
        tm *= SCALE;
#pragma unroll
        for (int off = 8; off >= 1; off >>= 1) tm = fmaxf(tm, __shfl_xor(tm, off));
        const float Mn = fmaxf(M[idx], tm);
        float ps = 0.f;
#pragma unroll
        for (int cf = 0; cf < 4; ++cf) ps += __expf(acc[rf][cf][r] * SCALE - Mn);
#pragma unroll
        for (int off = 8; off >= 1; off >>= 1) ps += __shfl_xor(ps, off);
        S[idx] = S[idx] * __expf(M[idx] - Mn) + ps;
        M[idx] = Mn;
#pragma unroll
        for (int cf = 0; cf < 4; ++cf)
          if (k0 + mt * 64 + cf * 16 + l15 == n) dval[idx] = acc[rf][cf][r] * SCALE;
      }
    }
  }

  // write partials: Mp[ks][b][n], Sp[ks][b][n]; dv[b][n] from the diag owner.
  float* Mp = part;
  float* Sp = part + 2 * BN;
  float* dv = part + 4 * BN;
#pragma unroll
  for (int rf = 0; rf < 2; ++rf)
#pragma unroll
    for (int r = 0; r < 4; ++r) {
      const int idx = rf * 4 + r;
      const int n = n0 + w * 32 + rf * 16 + l4 * 4 + r;
      if (l15 == l4 * 4 + r) {
        Mp[ks * BN + b * NDIM + n] = M[idx];
        Sp[ks * BN + b * NDIM + n] = S[idx];
        if ((n >> 9) == ks) dv[b * NDIM + n] = dval[idx];
      }
    }
}

// merge the two K-half partials into final diag probability.
__global__ __launch_bounds__(256) void merge_k(const float* __restrict__ part,
                                               float* __restrict__ outp) {
  const int gid = blockIdx.x * 256 + threadIdx.x;   // 0..BN
  const float M0 = part[gid], M1 = part[BN + gid];
  const float S0 = part[2 * BN + gid], S1 = part[3 * BN + gid];
  const float d = part[4 * BN + gid];
  const float Mf = fmaxf(M0, M1);
  const float Sf = S0 * __expf(M0 - Mf) + S1 * __expf(M1 - Mf);
  outp[gid] = __expf(d - Mf) / Sf;
}

extern "C" void kernel_launch(void* const* d_in, const int* in_sizes, int n_in,
                              void* d_out, int out_size, void* d_ws, size_t ws_size,
                              hipStream_t stream) {
  (void)in_sizes; (void)n_in; (void)out_size; (void)ws_size;
  const float* x     = (const float*)d_in[0];
  const float* y     = (const float*)d_in[1];
  const float* gamma = (const float*)d_in[2];
  const float* beta  = (const float*)d_in[3];
  const float* Wq    = (const float*)d_in[4];
  const float* Wk    = (const float*)d_in[5];
  const float* bq    = (const float*)d_in[6];
  const float* bk    = (const float*)d_in[7];
  float* out = (float*)d_out;

  unsigned short* wp = (unsigned short*)d_ws;
  unsigned short* planes = wp + 262144;
  float* part = (float*)(planes + 4 * BNC);

  wsplit_k<<<256, 256, 0, stream>>>(Wq, Wk, wp);

  dim3 g2(NDIM / 64, BATCH * 2);
  proj_k<<<g2, 256, 0, stream>>>(x, y, gamma, beta, bq, bk, wp, planes);

  attn_k<<<512, 256, 0, stream>>>(planes, part);

  merge_k<<<BN / 256, 256, 0, stream>>>(part, out);
}